// Round 5
// baseline (974.808 us; speedup 1.0000x reference)
//
#include <hip/hip_runtime.h>
#include <hip/hip_bf16.h>

#define SEQ 2048
#define DM  1024
#define DI  2048
#define DST 16
#define DTR 64
#define NVOC 32000
#define NC  128   // scan chunks
#define LC  16    // chunk length; NC*LC == SEQ

typedef __bf16 bf16x8 __attribute__((ext_vector_type(8)));
typedef float  f32x4  __attribute__((ext_vector_type(4)));

__device__ __forceinline__ float siluf(float x) { return x / (1.f + expf(-x)); }
__device__ __forceinline__ float softplusf(float x) {
    return fmaxf(x, 0.f) + log1pf(expf(-fabsf(x)));
}
__device__ __forceinline__ unsigned short f2bf(float f) {
    union { __hip_bfloat16 h; unsigned short u; } c;
    c.h = __float2bfloat16(f);
    return c.u;
}

// h[l,:] = embed[ids[l],:]
__global__ void embed_gather(const int* __restrict__ ids, const float* __restrict__ embed,
                             float* __restrict__ h) {
    int l = blockIdx.x;
    int row = ids[l];
    const float4* src = (const float4*)(embed + (size_t)row * DM);
    float4* dst = (float4*)(h + (size_t)l * DM);
    dst[threadIdx.x] = src[threadIdx.x];
}

// o[l,:] = x[l,:]*rsqrt(mean(x^2)+eps)*w[:]
// If ob != nullptr: write ONLY bf16 (f32 skipped). Else write f32.
__global__ void rmsnorm_kernel(const float* __restrict__ x, const float* __restrict__ w,
                               float* __restrict__ o, unsigned short* __restrict__ ob) {
    int l = blockIdx.x;
    int t = threadIdx.x; // 256
    float4 v = ((const float4*)(x + (size_t)l * DM))[t];
    float ss = v.x*v.x + v.y*v.y + v.z*v.z + v.w*v.w;
    #pragma unroll
    for (int m = 32; m; m >>= 1) ss += __shfl_xor(ss, m);
    __shared__ float red[4];
    if ((t & 63) == 0) red[t >> 6] = ss;
    __syncthreads();
    float tot = red[0] + red[1] + red[2] + red[3];
    float sc = rsqrtf(tot * (1.f / DM) + 1e-6f);
    float4 wv = ((const float4*)w)[t];
    float4 ov;
    ov.x = v.x * sc * wv.x;
    ov.y = v.y * sc * wv.y;
    ov.z = v.z * sc * wv.z;
    ov.w = v.w * sc * wv.w;
    if (ob) {
        uint2 pk;
        pk.x = (unsigned)f2bf(ov.x) | ((unsigned)f2bf(ov.y) << 16);
        pk.y = (unsigned)f2bf(ov.z) | ((unsigned)f2bf(ov.w) << 16);
        ((uint2*)(ob + (size_t)l * DM))[t] = pk;
    } else {
        ((float4*)(o + (size_t)l * DM))[t] = ov;
    }
}

// W fp32 [K][N] -> WT bf16 [Npad][K]; rows n>=N zero-filled
__global__ void transpose_f2bf(const float* __restrict__ W, unsigned short* __restrict__ WT,
                               int K, int N) {
    __shared__ float tile[32][33];
    int k0 = blockIdx.y * 32, n0 = blockIdx.x * 32;
    int tx = threadIdx.x;  // 32
    int ty = threadIdx.y;  // 8
    #pragma unroll
    for (int i = 0; i < 32; i += 8) {
        int n = n0 + tx;
        tile[ty + i][tx] = (n < N) ? W[(size_t)(k0 + ty + i) * N + n] : 0.f;
    }
    __syncthreads();
    #pragma unroll
    for (int i = 0; i < 32; i += 8)
        WT[(size_t)(n0 + ty + i) * K + k0 + tx] = f2bf(tile[tx][ty + i]);
}

// Generic fp32 GEMM (fallback only)
template<int ACT>
__global__ __launch_bounds__(256) void gemm_f32(const float* __restrict__ A, int lda,
                                                const float* __restrict__ B,
                                                const float* __restrict__ bias,
                                                const float* __restrict__ add,
                                                float* __restrict__ C,
                                                int M, int N, int K) {
    __shared__ float As[16][68];
    __shared__ float Bs[16][64];
    int tx = threadIdx.x, ty = threadIdx.y;
    int t = ty * 16 + tx;
    int m0 = blockIdx.y * 64, n0 = blockIdx.x * 64;
    float acc[4][4] = {};
    for (int k0 = 0; k0 < K; k0 += 16) {
        #pragma unroll
        for (int i = 0; i < 4; i++) {
            int idx = t + i * 256;
            int mm = idx >> 4, kk = idx & 15;
            As[kk][mm] = A[(size_t)(m0 + mm) * lda + k0 + kk];
            int nn = idx & 63, k2 = idx >> 6;
            Bs[k2][nn] = B[(size_t)(k0 + k2) * N + n0 + nn];
        }
        __syncthreads();
        #pragma unroll
        for (int kk = 0; kk < 16; kk++) {
            float4 a = *(const float4*)&As[kk][ty * 4];
            float4 b = *(const float4*)&Bs[kk][tx * 4];
            acc[0][0] += a.x*b.x; acc[0][1] += a.x*b.y; acc[0][2] += a.x*b.z; acc[0][3] += a.x*b.w;
            acc[1][0] += a.y*b.x; acc[1][1] += a.y*b.y; acc[1][2] += a.y*b.z; acc[1][3] += a.y*b.w;
            acc[2][0] += a.z*b.x; acc[2][1] += a.z*b.y; acc[2][2] += a.z*b.z; acc[2][3] += a.z*b.w;
            acc[3][0] += a.w*b.x; acc[3][1] += a.w*b.y; acc[3][2] += a.w*b.z; acc[3][3] += a.w*b.w;
        }
        __syncthreads();
    }
    #pragma unroll
    for (int i = 0; i < 4; i++) {
        int row = m0 + ty * 4 + i;
        float4 r;
        float* pr = &r.x;
        #pragma unroll
        for (int j = 0; j < 4; j++) {
            int col = n0 + tx * 4 + j;
            float v = acc[i][j];
            if (bias) v += bias[col];
            if (add)  v += add[(size_t)row * N + col];
            if (ACT == 1) v = softplusf(v);
            pr[j] = v;
        }
        *(float4*)&C[(size_t)row * N + n0 + tx * 4] = r;
    }
}

// bf16 MFMA GEMM: C(MxN,f32) = A(bf16 [M][lda]) @ BT(bf16 [N][K])^T
// 128x128 tile, BK=64, 256 threads = 4 waves (2x2), 4x4 frags of 16x16x32.
// LDS tiles [128][64] bf16 with st-style XOR swizzle (byte^=((byte>>9)&1)<<5):
// linear global_load_lds dest + pre-swizzled global source + swizzled ds_read.
// Epilogue: acc staged through LDS (2 rounds of 64x128 f32) -> float4 stores.
template<int BIAS, int ADD, int ACT, int DOUT>
__global__ __launch_bounds__(256) void gemm_bf16(const unsigned short* __restrict__ A, int lda,
                                                 const unsigned short* __restrict__ BT,
                                                 const float* __restrict__ bias,
                                                 const float* __restrict__ add,
                                                 float* __restrict__ C,
                                                 unsigned short* __restrict__ aux,
                                                 int M, int N, int K) {
    __shared__ unsigned short smem[2 * 128 * 64];   // As | Bs, 32 KB
    unsigned short* Asm = smem;
    unsigned short* Bsm = smem + 128 * 64;
    int t = threadIdx.x;
    int w = t >> 6, l = t & 63;
    int wm = w >> 1, wn = w & 1;
    int m0 = blockIdx.x * 128;
    int n0 = blockIdx.y * 128;
    int lr = l & 15, lk = (l >> 4) * 8;

    // staging source coords: for linear LDS byte x, fetch logical x^swz(x)
    int srow[4], scol[4];
    #pragma unroll
    for (int q = 0; q < 4; q++) {
        int lin = q * 4096 + w * 1024 + l * 16;
        int logi = lin ^ (((lin >> 9) & 1) << 5);
        srow[q] = logi >> 7;            // q*32 + w*8 + l/8
        scol[q] = (logi & 127) >> 1;    // element offset in K
    }
    // ds_read offsets (physical, in shorts)
    int aoff[4][2], boff[4][2];
    #pragma unroll
    for (int i = 0; i < 4; i++) {
        int ra = wm * 64 + i * 16 + lr;
        int rb = wn * 64 + i * 16 + lr;
        #pragma unroll
        for (int ks = 0; ks < 2; ks++) {
            int cb = ks * 64 + lk * 2;  // logical byte-in-row
            aoff[i][ks] = ra * 64 + ((cb ^ (((ra >> 2) & 1) << 5)) >> 1);
            boff[i][ks] = rb * 64 + ((cb ^ (((rb >> 2) & 1) << 5)) >> 1);
        }
    }
    f32x4 acc[4][4] = {};
    for (int k0 = 0; k0 < K; k0 += 64) {
        #pragma unroll
        for (int q = 0; q < 4; q++) {
            const unsigned short* ga = A  + (size_t)(m0 + srow[q]) * lda + k0 + scol[q];
            const unsigned short* gb = BT + (size_t)(n0 + srow[q]) * K  + k0 + scol[q];
            __builtin_amdgcn_global_load_lds((const __attribute__((address_space(1))) void*)ga,
                (__attribute__((address_space(3))) void*)(Asm + q * 2048 + w * 512), 16, 0, 0);
            __builtin_amdgcn_global_load_lds((const __attribute__((address_space(1))) void*)gb,
                (__attribute__((address_space(3))) void*)(Bsm + q * 2048 + w * 512), 16, 0, 0);
        }
        __syncthreads();
        #pragma unroll
        for (int ks = 0; ks < 2; ks++) {
            bf16x8 af[4], bfr[4];
            #pragma unroll
            for (int i = 0; i < 4; i++) {
                af[i]  = *reinterpret_cast<const bf16x8*>(&Asm[aoff[i][ks]]);
                bfr[i] = *reinterpret_cast<const bf16x8*>(&Bsm[boff[i][ks]]);
            }
            #pragma unroll
            for (int i = 0; i < 4; i++)
                #pragma unroll
                for (int j = 0; j < 4; j++)
                    acc[i][j] = __builtin_amdgcn_mfma_f32_16x16x32_bf16(af[i], bfr[j], acc[i][j], 0, 0, 0);
        }
        __syncthreads();
    }
    // ---- epilogue: LDS transpose (2 rounds of 64 rows), float4 coalesced stores ----
    float* cf = (float*)smem;   // [64][128] f32 = 32 KB
    int cr = (l >> 4) * 4;
    #pragma unroll
    for (int r = 0; r < 2; r++) {
        if (wm == r) {
            #pragma unroll
            for (int i = 0; i < 4; i++)
                #pragma unroll
                for (int j = 0; j < 4; j++) {
                    int col = wn * 64 + j * 16 + lr;
                    #pragma unroll
                    for (int rr = 0; rr < 4; rr++)
                        cf[(i * 16 + cr + rr) * 128 + col] = acc[i][j][rr];
                }
        }
        __syncthreads();
        int col4 = (t & 31) * 4;
        #pragma unroll
        for (int rep = 0; rep < 8; rep++) {
            int row = (t >> 5) + rep * 8;           // 0..63
            float4 v = ((const float4*)cf)[row * 32 + (t & 31)];
            int grow = m0 + r * 64 + row;
            int gcol = n0 + col4;
            if (BIAS) {
                float4 bv = *(const float4*)&bias[gcol];
                v.x += bv.x; v.y += bv.y; v.z += bv.z; v.w += bv.w;
            }
            if (ADD) {
                float4 av = *(const float4*)&add[(size_t)grow * N + gcol];
                v.x += av.x; v.y += av.y; v.z += av.z; v.w += av.w;
            }
            if (DOUT) {
                if (gcol < 64) {
                    uint2 pk;
                    pk.x = (unsigned)f2bf(v.x) | ((unsigned)f2bf(v.y) << 16);
                    pk.y = (unsigned)f2bf(v.z) | ((unsigned)f2bf(v.w) << 16);
                    *(uint2*)&aux[(size_t)grow * 64 + gcol] = pk;
                }
            }
            if (ACT == 1) {
                v.x = softplusf(v.x); v.y = softplusf(v.y);
                v.z = softplusf(v.z); v.w = softplusf(v.w);
            }
            *(float4*)&C[(size_t)grow * N + gcol] = v;
        }
        __syncthreads();
    }
}

// xc[l,d] = silu(conv_b[l] + sum_k x[l, d+k-1]*conv_w[k,l])   (conv over d!)
__global__ void conv_silu_kernel(const float* __restrict__ xr, const float* __restrict__ cw,
                                 const float* __restrict__ cb, float* __restrict__ xc) {
    int idx = blockIdx.x * 256 + threadIdx.x;
    int l = idx >> 11, d = idx & 2047;
    float acc = cb[l];
    const float* xrow = xr + (size_t)l * 4096;
    #pragma unroll
    for (int k = 0; k < 4; k++) {
        int c = d + k - 1;
        if (c >= 0 && c < DI) acc += xrow[c] * cw[k * SEQ + l];
    }
    xc[idx] = siluf(acc);
}

// fallback xproj (fp32, stride-128 output)
__global__ void xproj_kernel(const float* __restrict__ u, const float* __restrict__ xw,
                             float* __restrict__ xdbl) {
    int l0 = blockIdx.x * 4;
    int t = threadIdx.x; // 128
    __shared__ float us[4][DM];
    for (int i = t; i < 4 * DM; i += 128) us[i >> 10][i & 1023] = u[(size_t)l0 * DM + i];
    __syncthreads();
    if (t < 96) {
        float a0 = 0.f, a1 = 0.f, a2 = 0.f, a3 = 0.f;
        for (int k = 0; k < DM; k++) {
            float wv = xw[(size_t)k * 96 + t];
            a0 += us[0][k] * wv; a1 += us[1][k] * wv;
            a2 += us[2][k] * wv; a3 += us[3][k] * wv;
        }
        xdbl[(size_t)(l0 + 0) * 128 + t] = a0;
        xdbl[(size_t)(l0 + 1) * 128 + t] = a1;
        xdbl[(size_t)(l0 + 2) * 128 + t] = a2;
        xdbl[(size_t)(l0 + 3) * 128 + t] = a3;
    }
}

// ---- chunked selective scan ----
__global__ __launch_bounds__(256) void scan_p1(const float* __restrict__ xc,
        const float* __restrict__ delta, const float* __restrict__ xdbl,
        const float* __restrict__ A_log, float* __restrict__ P, float* __restrict__ S) {
    int c = blockIdx.x;
    int d = blockIdx.y * 256 + threadIdx.x;
    int l0 = c * LC;
    __shared__ float Bsh[LC][16];
    {
        int t = threadIdx.x;   // 256 = LC*16 exactly
        int ll = t >> 4, q = t & 15;
        Bsh[ll][q] = xdbl[(size_t)(l0 + ll) * 128 + 64 + q];
    }
    __syncthreads();
    float a[16];
    #pragma unroll
    for (int i = 0; i < 4; i++) {
        float4 al = ((const float4*)(A_log + (size_t)d * 16))[i];
        a[4*i+0] = -expf(al.x); a[4*i+1] = -expf(al.y);
        a[4*i+2] = -expf(al.z); a[4*i+3] = -expf(al.w);
    }
    float s[16] = {};
    float sumdv = 0.f;
    for (int ll = 0; ll < LC; ll++) {
        float dv = delta[(size_t)(l0 + ll) * DI + d];
        float xv = xc[(size_t)(l0 + ll) * DI + d];
        float du = dv * xv;
        sumdv += dv;
        #pragma unroll
        for (int n = 0; n < 16; n++)
            s[n] = expf(dv * a[n]) * s[n] + du * Bsh[ll][n];
    }
    size_t o = ((size_t)c * DI + d) * 16;
    #pragma unroll
    for (int i = 0; i < 4; i++) {
        float4 sv = make_float4(s[4*i], s[4*i+1], s[4*i+2], s[4*i+3]);
        float4 pv = make_float4(expf(a[4*i]*sumdv), expf(a[4*i+1]*sumdv),
                                expf(a[4*i+2]*sumdv), expf(a[4*i+3]*sumdv));
        ((float4*)(S + o))[i] = sv;
        ((float4*)(P + o))[i] = pv;
    }
}

__global__ void scan_p2(const float* __restrict__ P, const float* __restrict__ S,
                        float* __restrict__ X) {
    int t = blockIdx.x * 256 + threadIdx.x;   // 0 .. DI*16-1
    float x = 0.f;
    #pragma unroll 16
    for (int c = 0; c < NC; c++) {
        X[(size_t)c * (DI*16) + t] = x;
        x = P[(size_t)c * (DI*16) + t] * x + S[(size_t)c * (DI*16) + t];
    }
}

__global__ __launch_bounds__(256) void scan_p3(const float* __restrict__ xc,
        const float* __restrict__ delta, const float* __restrict__ xdbl,
        const float* __restrict__ A_log, const float* __restrict__ Dp,
        const float* __restrict__ X, const float* __restrict__ xr,
        float* __restrict__ y, unsigned short* __restrict__ yb) {
    int c = blockIdx.x;
    int d = blockIdx.y * 256 + threadIdx.x;
    int l0 = c * LC;
    __shared__ float Bsh[LC][16], Csh[LC][16];
    {
        int t = threadIdx.x;
        int ll = t >> 4, q = t & 15;
        size_t row = (size_t)(l0 + ll) * 128;
        Bsh[ll][q] = xdbl[row + 64 + q];
        Csh[ll][q] = xdbl[row + 80 + q];
    }
    __syncthreads();
    float a[16];
    #pragma unroll
    for (int i = 0; i < 4; i++) {
        float4 al = ((const float4*)(A_log + (size_t)d * 16))[i];
        a[4*i+0] = -expf(al.x); a[4*i+1] = -expf(al.y);
        a[4*i+2] = -expf(al.z); a[4*i+3] = -expf(al.w);
    }
    float s[16];
    size_t o = ((size_t)c * DI + d) * 16;
    #pragma unroll
    for (int i = 0; i < 4; i++) {
        float4 xv4 = ((const float4*)(X + o))[i];
        s[4*i] = xv4.x; s[4*i+1] = xv4.y; s[4*i+2] = xv4.z; s[4*i+3] = xv4.w;
    }
    float Dv = Dp[d];
    for (int ll = 0; ll < LC; ll++) {
        size_t lrow = (size_t)(l0 + ll);
        float dv = delta[lrow * DI + d];
        float xv = xc[lrow * DI + d];
        float du = dv * xv;
        float yv = 0.f;
        #pragma unroll
        for (int n = 0; n < 16; n++) {
            s[n] = expf(dv * a[n]) * s[n] + du * Bsh[ll][n];
            yv += s[n] * Csh[ll][n];
        }
        float val = yv + xv * Dv;
        if (yb) {
            float res = xr[lrow * 4096 + 2048 + d];
            yb[lrow * DI + d] = f2bf(val * siluf(res));
        } else {
            y[lrow * DI + d] = val;
        }
    }
}

// fallback: y *= silu(res)
__global__ void ymul_silu(float* __restrict__ y, const float* __restrict__ xr) {
    int idx = blockIdx.x * 256 + threadIdx.x;
    int l = idx >> 11, d = idx & 2047;
    float res = xr[(size_t)l * 4096 + 2048 + d];
    y[idx] = y[idx] * siluf(res);
}

extern "C" void kernel_launch(void* const* d_in, const int* in_sizes, int n_in,
                              void* d_out, int out_size, void* d_ws, size_t ws_size,
                              hipStream_t stream) {
    const int*   ids        = (const int*)d_in[0];
    const float* embed      = (const float*)d_in[1];
    const float* norm_scale = (const float*)d_in[2];
    const float* in_w       = (const float*)d_in[3];
    const float* in_b       = (const float*)d_in[4];
    const float* conv_w     = (const float*)d_in[5];
    const float* conv_b     = (const float*)d_in[6];
    const float* x_proj_w   = (const float*)d_in[7];
    const float* dt_w       = (const float*)d_in[8];
    const float* dt_b       = (const float*)d_in[9];
    const float* out_w      = (const float*)d_in[10];
    const float* out_b      = (const float*)d_in[11];
    const float* A_log      = (const float*)d_in[12];
    const float* Dp         = (const float*)d_in[13];
    const float* norm_f     = (const float*)d_in[14];
    const float* lm_w       = (const float*)d_in[15];

    float* out = (float*)d_out;

    // ---- workspace layout ----
    char* p = (char*)d_ws;
    float* h  = (float*)p;  p += (size_t)SEQ * DM * 4;
    float* hn = (float*)p;  p += (size_t)SEQ * DM * 4;
    size_t base = (size_t)p - (size_t)d_ws;
    const size_t SZ_UB    = (size_t)SEQ * DM * 2;
    const size_t SZ_YB    = (size_t)SEQ * DI * 2;
    const size_t SZ_HNB   = (size_t)SEQ * DM * 2;
    const size_t SZ_DB    = (size_t)SEQ * 64 * 2;
    const size_t SZ_INWT  = (size_t)2 * 4096 * DM * 2;
    const size_t SZ_OUTWT = (size_t)2 * DM * DI * 2;
    const size_t SZ_XPWT  = (size_t)2 * 128 * DM * 2;
    const size_t SZ_DTWT  = (size_t)2 * DI * 64 * 2;
    const size_t SZ_LMWT  = (size_t)NVOC * DM * 2;
    size_t need_mid  = base + SZ_UB + SZ_YB + SZ_HNB + SZ_DB + SZ_INWT + SZ_OUTWT + SZ_XPWT + SZ_DTWT;
    size_t need_full = need_mid + SZ_LMWT;
    bool mid  = ws_size >= need_mid;
    bool full = ws_size >= need_full;

    unsigned short *u_b = nullptr, *y_b = nullptr, *hn_b = nullptr, *dlt_b = nullptr;
    unsigned short *in_wT = nullptr, *out_wT = nullptr, *xp_wT = nullptr, *dt_wT = nullptr, *lm_wT = nullptr;
    if (mid) {
        u_b    = (unsigned short*)p; p += SZ_UB;
        y_b    = (unsigned short*)p; p += SZ_YB;
        hn_b   = (unsigned short*)p; p += SZ_HNB;
        dlt_b  = (unsigned short*)p; p += SZ_DB;
        in_wT  = (unsigned short*)p; p += SZ_INWT;
        out_wT = (unsigned short*)p; p += SZ_OUTWT;
        xp_wT  = (unsigned short*)p; p += SZ_XPWT;
        dt_wT  = (unsigned short*)p; p += SZ_DTWT;
        if (full) { lm_wT = (unsigned short*)p; p += SZ_LMWT; }
    }

    // transient scratch inside d_out (fully rewritten by final GEMM)
    float* u     = out;                          // SEQ*DM (fallback only)
    float* xr    = u + (size_t)SEQ * DM;         // SEQ*4096
    float* xc    = xr + (size_t)SEQ * 4096;      // SEQ*DI
    float* xdbl  = xc + (size_t)SEQ * DI;        // SEQ*128
    float* delta = xdbl + (size_t)SEQ * 128;     // SEQ*DI
    float* y     = delta + (size_t)SEQ * DI;     // SEQ*DI (fallback only)
    float* Pbuf  = y + (size_t)SEQ * DI;         // NC*DI*16
    float* Sbuf  = Pbuf + (size_t)NC * DI * 16;  // NC*DI*16
    float* Xbuf  = Sbuf + (size_t)NC * DI * 16;  // NC*DI*16

    // ---- weight convert+transpose (per call; deterministic) ----
    if (mid) {
        for (int L = 0; L < 2; L++) {
            transpose_f2bf<<<dim3(4096 / 32, DM / 32), dim3(32, 8), 0, stream>>>(
                in_w + (size_t)L * DM * 4096, in_wT + (size_t)L * 4096 * DM, DM, 4096);
            transpose_f2bf<<<dim3(DM / 32, DI / 32), dim3(32, 8), 0, stream>>>(
                out_w + (size_t)L * DI * DM, out_wT + (size_t)L * DM * DI, DI, DM);
            transpose_f2bf<<<dim3(128 / 32, DM / 32), dim3(32, 8), 0, stream>>>(
                x_proj_w + (size_t)L * DM * 96, xp_wT + (size_t)L * 128 * DM, DM, 96);
            transpose_f2bf<<<dim3(DI / 32, 64 / 32), dim3(32, 8), 0, stream>>>(
                dt_w + (size_t)L * DTR * DI, dt_wT + (size_t)L * DI * 64, DTR, DI);
        }
        if (full)
            transpose_f2bf<<<dim3(NVOC / 32, DM / 32), dim3(32, 8), 0, stream>>>(
                lm_w, lm_wT, DM, NVOC);
    }

    embed_gather<<<SEQ, 256, 0, stream>>>(ids, embed, h);

    for (int L = 0; L < 2; L++) {
        rmsnorm_kernel<<<SEQ, 256, 0, stream>>>(h, norm_scale + (size_t)L * DM, u, u_b);
        if (mid) {
            gemm_bf16<1, 0, 0, 0><<<dim3(SEQ / 128, 4096 / 128), 256, 0, stream>>>(
                u_b, DM, in_wT + (size_t)L * 4096 * DM, in_b + (size_t)L * 4096, nullptr, xr,
                nullptr, SEQ, 4096, DM);
        } else {
            gemm_f32<0><<<dim3(4096 / 64, SEQ / 64), dim3(16, 16), 0, stream>>>(
                u, DM, in_w + (size_t)L * DM * 4096, in_b + (size_t)L * 4096, nullptr, xr,
                SEQ, 4096, DM);
        }
        conv_silu_kernel<<<SEQ * DI / 256, 256, 0, stream>>>(
            xr, conv_w + (size_t)L * 4 * SEQ, conv_b + (size_t)L * SEQ, xc);
        if (mid) {
            gemm_bf16<0, 0, 0, 1><<<dim3(SEQ / 128, 1), 256, 0, stream>>>(
                u_b, DM, xp_wT + (size_t)L * 128 * DM, nullptr, nullptr, xdbl,
                dlt_b, SEQ, 128, DM);
            gemm_bf16<1, 0, 1, 0><<<dim3(SEQ / 128, DI / 128), 256, 0, stream>>>(
                dlt_b, 64, dt_wT + (size_t)L * DI * 64, dt_b + (size_t)L * DI, nullptr, delta,
                nullptr, SEQ, DI, 64);
        } else {
            xproj_kernel<<<SEQ / 4, 128, 0, stream>>>(u, x_proj_w + (size_t)L * DM * 96, xdbl);
            gemm_f32<1><<<dim3(DI / 64, SEQ / 64), dim3(16, 16), 0, stream>>>(
                xdbl, 128, dt_w + (size_t)L * DTR * DI, dt_b + (size_t)L * DI, nullptr, delta,
                SEQ, DI, DTR);
        }
        scan_p1<<<dim3(NC, DI / 256), 256, 0, stream>>>(
            xc, delta, xdbl, A_log + (size_t)L * DI * DST, Pbuf, Sbuf);
        scan_p2<<<DI * 16 / 256, 256, 0, stream>>>(Pbuf, Sbuf, Xbuf);
        scan_p3<<<dim3(NC, DI / 256), 256, 0, stream>>>(
            xc, delta, xdbl, A_log + (size_t)L * DI * DST, Dp + (size_t)L * DI, Xbuf, xr,
            y, y_b);
        if (mid) {
            gemm_bf16<1, 1, 0, 0><<<dim3(SEQ / 128, DM / 128), 256, 0, stream>>>(
                y_b, DI, out_wT + (size_t)L * DM * DI, out_b + (size_t)L * DM, h, h,
                nullptr, SEQ, DM, DI);
        } else {
            ymul_silu<<<SEQ * DI / 256, 256, 0, stream>>>(y, xr);
            gemm_f32<0><<<dim3(DM / 64, SEQ / 64), dim3(16, 16), 0, stream>>>(
                y, DI, out_w + (size_t)L * DI * DM, out_b + (size_t)L * DM, h, h,
                SEQ, DM, DI);
        }
    }

    rmsnorm_kernel<<<SEQ, 256, 0, stream>>>(h, norm_f, hn, full ? hn_b : nullptr);
    if (full) {
        gemm_bf16<0, 0, 0, 0><<<dim3(SEQ / 128, NVOC / 128), 256, 0, stream>>>(
            hn_b, DM, lm_wT, nullptr, nullptr, out, nullptr, SEQ, NVOC, DM);
    } else {
        gemm_f32<0><<<dim3(NVOC / 64, SEQ / 64), dim3(16, 16), 0, stream>>>(
            hn, DM, lm_w, nullptr, nullptr, out, SEQ, NVOC, DM);
    }
}

// Round 6
// 867.011 us; speedup vs baseline: 1.1243x; 1.1243x over previous
//
#include <hip/hip_runtime.h>
#include <hip/hip_bf16.h>

#define SEQ 2048
#define DM  1024
#define DI  2048
#define DST 16
#define DTR 64
#define NVOC 32000
#define NC  128   // scan chunks
#define LC  16    // chunk length; NC*LC == SEQ

typedef __bf16 bf16x8 __attribute__((ext_vector_type(8)));
typedef float  f32x4  __attribute__((ext_vector_type(4)));

__device__ __forceinline__ float siluf(float x) { return x / (1.f + expf(-x)); }
__device__ __forceinline__ float softplusf(float x) {
    return fmaxf(x, 0.f) + log1pf(expf(-fabsf(x)));
}
__device__ __forceinline__ unsigned short f2bf(float f) {
    union { __hip_bfloat16 h; unsigned short u; } c;
    c.h = __float2bfloat16(f);
    return c.u;
}

// h[l,:] = embed[ids[l],:]
__global__ void embed_gather(const int* __restrict__ ids, const float* __restrict__ embed,
                             float* __restrict__ h) {
    int l = blockIdx.x;
    int row = ids[l];
    const float4* src = (const float4*)(embed + (size_t)row * DM);
    float4* dst = (float4*)(h + (size_t)l * DM);
    dst[threadIdx.x] = src[threadIdx.x];
}

// o[l,:] = x[l,:]*rsqrt(mean(x^2)+eps)*w[:]
// If ob != nullptr: write ONLY bf16 (f32 skipped). Else write f32.
__global__ void rmsnorm_kernel(const float* __restrict__ x, const float* __restrict__ w,
                               float* __restrict__ o, unsigned short* __restrict__ ob) {
    int l = blockIdx.x;
    int t = threadIdx.x; // 256
    float4 v = ((const float4*)(x + (size_t)l * DM))[t];
    float ss = v.x*v.x + v.y*v.y + v.z*v.z + v.w*v.w;
    #pragma unroll
    for (int m = 32; m; m >>= 1) ss += __shfl_xor(ss, m);
    __shared__ float red[4];
    if ((t & 63) == 0) red[t >> 6] = ss;
    __syncthreads();
    float tot = red[0] + red[1] + red[2] + red[3];
    float sc = rsqrtf(tot * (1.f / DM) + 1e-6f);
    float4 wv = ((const float4*)w)[t];
    float4 ov;
    ov.x = v.x * sc * wv.x;
    ov.y = v.y * sc * wv.y;
    ov.z = v.z * sc * wv.z;
    ov.w = v.w * sc * wv.w;
    if (ob) {
        uint2 pk;
        pk.x = (unsigned)f2bf(ov.x) | ((unsigned)f2bf(ov.y) << 16);
        pk.y = (unsigned)f2bf(ov.z) | ((unsigned)f2bf(ov.w) << 16);
        ((uint2*)(ob + (size_t)l * DM))[t] = pk;
    } else {
        ((float4*)(o + (size_t)l * DM))[t] = ov;
    }
}

// W fp32 [K][N] -> WT bf16 [Npad][K]; rows n>=N zero-filled
__global__ void transpose_f2bf(const float* __restrict__ W, unsigned short* __restrict__ WT,
                               int K, int N) {
    __shared__ float tile[32][33];
    int k0 = blockIdx.y * 32, n0 = blockIdx.x * 32;
    int tx = threadIdx.x;  // 32
    int ty = threadIdx.y;  // 8
    #pragma unroll
    for (int i = 0; i < 32; i += 8) {
        int n = n0 + tx;
        tile[ty + i][tx] = (n < N) ? W[(size_t)(k0 + ty + i) * N + n] : 0.f;
    }
    __syncthreads();
    #pragma unroll
    for (int i = 0; i < 32; i += 8)
        WT[(size_t)(n0 + ty + i) * K + k0 + tx] = f2bf(tile[tx][ty + i]);
}

// Generic fp32 GEMM (fallback only)
template<int ACT>
__global__ __launch_bounds__(256) void gemm_f32(const float* __restrict__ A, int lda,
                                                const float* __restrict__ B,
                                                const float* __restrict__ bias,
                                                const float* __restrict__ add,
                                                float* __restrict__ C,
                                                int M, int N, int K) {
    __shared__ float As[16][68];
    __shared__ float Bs[16][64];
    int tx = threadIdx.x, ty = threadIdx.y;
    int t = ty * 16 + tx;
    int m0 = blockIdx.y * 64, n0 = blockIdx.x * 64;
    float acc[4][4] = {};
    for (int k0 = 0; k0 < K; k0 += 16) {
        #pragma unroll
        for (int i = 0; i < 4; i++) {
            int idx = t + i * 256;
            int mm = idx >> 4, kk = idx & 15;
            As[kk][mm] = A[(size_t)(m0 + mm) * lda + k0 + kk];
            int nn = idx & 63, k2 = idx >> 6;
            Bs[k2][nn] = B[(size_t)(k0 + k2) * N + n0 + nn];
        }
        __syncthreads();
        #pragma unroll
        for (int kk = 0; kk < 16; kk++) {
            float4 a = *(const float4*)&As[kk][ty * 4];
            float4 b = *(const float4*)&Bs[kk][tx * 4];
            acc[0][0] += a.x*b.x; acc[0][1] += a.x*b.y; acc[0][2] += a.x*b.z; acc[0][3] += a.x*b.w;
            acc[1][0] += a.y*b.x; acc[1][1] += a.y*b.y; acc[1][2] += a.y*b.z; acc[1][3] += a.y*b.w;
            acc[2][0] += a.z*b.x; acc[2][1] += a.z*b.y; acc[2][2] += a.z*b.z; acc[2][3] += a.z*b.w;
            acc[3][0] += a.w*b.x; acc[3][1] += a.w*b.y; acc[3][2] += a.w*b.z; acc[3][3] += a.w*b.w;
        }
        __syncthreads();
    }
    #pragma unroll
    for (int i = 0; i < 4; i++) {
        int row = m0 + ty * 4 + i;
        float4 r;
        float* pr = &r.x;
        #pragma unroll
        for (int j = 0; j < 4; j++) {
            int col = n0 + tx * 4 + j;
            float v = acc[i][j];
            if (bias) v += bias[col];
            if (add)  v += add[(size_t)row * N + col];
            if (ACT == 1) v = softplusf(v);
            pr[j] = v;
        }
        *(float4*)&C[(size_t)row * N + n0 + tx * 4] = r;
    }
}

// bf16 MFMA GEMM (R3-proven m97 structure): C(MxN,f32) = A(bf16 [M][lda]) @ BT(bf16 [N][K])^T
// 128x128 tile, BK=32, 256 threads = 4 waves (2x2), 4x4 fragments of 16x16x32.
// DOUT: also write bf16 of cols 0..63 to aux[row*64+col] (pre-activation).
template<int BIAS, int ADD, int ACT, int DOUT>
__global__ __launch_bounds__(256) void gemm_bf16(const unsigned short* __restrict__ A, int lda,
                                                 const unsigned short* __restrict__ BT,
                                                 const float* __restrict__ bias,
                                                 const float* __restrict__ add,
                                                 float* __restrict__ C,
                                                 unsigned short* __restrict__ aux,
                                                 int M, int N, int K) {
    __shared__ unsigned short As[128 * 32];
    __shared__ unsigned short Bs[128 * 32];
    int t = threadIdx.x;
    int w = t >> 6, l = t & 63;
    int wm = w >> 1, wn = w & 1;
    int m0 = blockIdx.x * 128;   // M-tiles on x: consecutive blocks share B panel (L2)
    int n0 = blockIdx.y * 128;
    int lr = l & 15, lk = (l >> 4) * 8;
    int sr = t >> 2, sc = (t & 3) * 8;     // staging: row, k-offset
    f32x4 acc[4][4] = {};
    for (int k0 = 0; k0 < K; k0 += 32) {
        const unsigned short* ga = A  + (size_t)(m0 + sr) * lda + k0 + sc;
        const unsigned short* gb = BT + (size_t)(n0 + sr) * K + k0 + sc;
        unsigned short* la = As + w * 512;   // wave-uniform base; HW adds lane*16B
        unsigned short* lb = Bs + w * 512;
        __builtin_amdgcn_global_load_lds((const __attribute__((address_space(1))) void*)ga,
            (__attribute__((address_space(3))) void*)la, 16, 0, 0);
        __builtin_amdgcn_global_load_lds((const __attribute__((address_space(1))) void*)(ga + (size_t)64 * lda),
            (__attribute__((address_space(3))) void*)(la + 2048), 16, 0, 0);
        __builtin_amdgcn_global_load_lds((const __attribute__((address_space(1))) void*)gb,
            (__attribute__((address_space(3))) void*)(lb), 16, 0, 0);
        __builtin_amdgcn_global_load_lds((const __attribute__((address_space(1))) void*)(gb + (size_t)64 * K),
            (__attribute__((address_space(3))) void*)(lb + 2048), 16, 0, 0);
        __syncthreads();
        bf16x8 af[4], bfr[4];
        #pragma unroll
        for (int i = 0; i < 4; i++) {
            af[i]  = *reinterpret_cast<const bf16x8*>(&As[(wm * 64 + i * 16 + lr) * 32 + lk]);
            bfr[i] = *reinterpret_cast<const bf16x8*>(&Bs[(wn * 64 + i * 16 + lr) * 32 + lk]);
        }
        #pragma unroll
        for (int i = 0; i < 4; i++)
            #pragma unroll
            for (int j = 0; j < 4; j++)
                acc[i][j] = __builtin_amdgcn_mfma_f32_16x16x32_bf16(af[i], bfr[j], acc[i][j], 0, 0, 0);
        __syncthreads();
    }
    int cr = (l >> 4) * 4;
    #pragma unroll
    for (int i = 0; i < 4; i++) {
        #pragma unroll
        for (int j = 0; j < 4; j++) {
            int col = n0 + wn * 64 + j * 16 + lr;
            float bv = BIAS ? bias[col] : 0.f;
            #pragma unroll
            for (int rr = 0; rr < 4; rr++) {
                int row = m0 + wm * 64 + i * 16 + cr + rr;
                float v = acc[i][j][rr] + bv;
                if (ADD) v += add[(size_t)row * N + col];
                if (DOUT) { if (col < 64) aux[(size_t)row * 64 + col] = f2bf(v); }
                if (ACT == 1) v = softplusf(v);
                C[(size_t)row * N + col] = v;
            }
        }
    }
}

// ============ 256x256 8-phase bf16 GEMM (T2 swizzle + T3/T4 + T5) ============
// C(MxN,f32) = A(bf16 [M][K]) @ BT(bf16 [N][K])^T, no bias/add/act.
// BK=64, 512 threads = 8 waves (2M x 4N), wave tile 128x64, acc[8][4] f32x4.
// LDS 128 KiB dynamic: A dbuf 2x[256][64], B dbuf 2x[256][64] bf16.
// Swizzle (both sides): phys_col_byte = logical ^ ((row&7)<<4)  -> 2-way max.
// Staging: pre-swizzled global source + linear global_load_lds dest.
// Per K-tile: 4 phases {ds_read frags | stage | s_barrier | setprio MFMA x16 |
// s_barrier}; stages of kt+1 issued in phases 0-1; single vmcnt(0) at group end.
__global__ __launch_bounds__(512, 1) void gemm_bf16_8ph(
        const unsigned short* __restrict__ A,
        const unsigned short* __restrict__ BT,
        float* __restrict__ C, int M, int N, int K) {
    extern __shared__ unsigned short lds[];   // [A0|A1|B0|B1] x 16384 shorts
    const int t = threadIdx.x;
    const int w = t >> 6, l = t & 63;
    const int wr = w >> 2, wc = w & 3;
    const int m0 = blockIdx.x * 256, n0 = blockIdx.y * 256;
    const int lane8 = l >> 3, lane7 = l & 7;
    const int swz = (lane7 ^ lane8) * 8;                  // staging k-offset (elements)
    const int colS0 = ((l >> 4) * 8) ^ (lane7 << 3);      // ds_read col (shorts), ks=0
    const int colS1 = (32 + ((l >> 4) * 8)) ^ (lane7 << 3); // ks=1
    const int rowA = wr * 128 + (l & 15);
    const int rowB = wc * 64 + (l & 15);
    const int srow = w * 8 + lane8;                       // staging row (+q*64)
    const int NT = K >> 6;
    f32x4 acc[8][4] = {};
    bf16x8 af[4], bf[4];

    // prologue: stage K-tile 0 into buf0 (A halves + B halves, 8 loads)
    {
        const unsigned short* a0 = A + (size_t)(m0 + srow) * K + swz;
        const unsigned short* b0 = BT + (size_t)(n0 + srow) * K + swz;
        #pragma unroll
        for (int q = 0; q < 4; q++) {
            __builtin_amdgcn_global_load_lds(
                (const __attribute__((address_space(1))) void*)(a0 + (size_t)q * 64 * K),
                (__attribute__((address_space(3))) void*)(lds + q * 4096 + w * 512), 16, 0, 0);
            __builtin_amdgcn_global_load_lds(
                (const __attribute__((address_space(1))) void*)(b0 + (size_t)q * 64 * K),
                (__attribute__((address_space(3))) void*)(lds + 32768 + q * 4096 + w * 512), 16, 0, 0);
        }
        asm volatile("s_waitcnt vmcnt(0)" ::: "memory");
        __builtin_amdgcn_s_barrier();
    }

    for (int kt = 0; kt < NT; kt++) {
        const unsigned short* AC = lds + (kt & 1) * 16384;
        const unsigned short* BC = lds + 32768 + (kt & 1) * 16384;
        unsigned short* AN = lds + ((kt & 1) ^ 1) * 16384;
        unsigned short* BN = lds + 32768 + ((kt & 1) ^ 1) * 16384;
        const bool st = (kt + 1 < NT);
        const unsigned short* aS = A + (size_t)(m0 + srow) * K + ((kt + 1) << 6) + swz;
        const unsigned short* bS = BT + (size_t)(n0 + srow) * K + ((kt + 1) << 6) + swz;

        // -------- phase 0: qa=0, ks=0; stage A(kt+1) both halves --------
        #pragma unroll
        for (int i = 0; i < 4; i++)
            af[i] = *reinterpret_cast<const bf16x8*>(&AC[(rowA + i * 16) * 64 + colS0]);
        #pragma unroll
        for (int j = 0; j < 4; j++)
            bf[j] = *reinterpret_cast<const bf16x8*>(&BC[(rowB + j * 16) * 64 + colS0]);
        if (st) {
            #pragma unroll
            for (int q = 0; q < 4; q++)
                __builtin_amdgcn_global_load_lds(
                    (const __attribute__((address_space(1))) void*)(aS + (size_t)q * 64 * K),
                    (__attribute__((address_space(3))) void*)(AN + q * 4096 + w * 512), 16, 0, 0);
        }
        __builtin_amdgcn_s_barrier();
        __builtin_amdgcn_s_setprio(1);
        #pragma unroll
        for (int i = 0; i < 4; i++)
            #pragma unroll
            for (int j = 0; j < 4; j++)
                acc[i][j] = __builtin_amdgcn_mfma_f32_16x16x32_bf16(af[i], bf[j], acc[i][j], 0, 0, 0);
        __builtin_amdgcn_s_setprio(0);
        __builtin_amdgcn_s_barrier();

        // -------- phase 1: qa=1, ks=0; stage B(kt+1) both halves --------
        #pragma unroll
        for (int i = 0; i < 4; i++)
            af[i] = *reinterpret_cast<const bf16x8*>(&AC[(rowA + 64 + i * 16) * 64 + colS0]);
        if (st) {
            #pragma unroll
            for (int q = 0; q < 4; q++)
                __builtin_amdgcn_global_load_lds(
                    (const __attribute__((address_space(1))) void*)(bS + (size_t)q * 64 * K),
                    (__attribute__((address_space(3))) void*)(BN + q * 4096 + w * 512), 16, 0, 0);
        }
        __builtin_amdgcn_s_barrier();
        __builtin_amdgcn_s_setprio(1);
        #pragma unroll
        for (int i = 0; i < 4; i++)
            #pragma unroll
            for (int j = 0; j < 4; j++)
                acc[4 + i][j] = __builtin_amdgcn_mfma_f32_16x16x32_bf16(af[i], bf[j], acc[4 + i][j], 0, 0, 0);
        __builtin_amdgcn_s_setprio(0);
        __builtin_amdgcn_s_barrier();

        // -------- phase 2: qa=0, ks=1 --------
        #pragma unroll
        for (int i = 0; i < 4; i++)
            af[i] = *reinterpret_cast<const bf16x8*>(&AC[(rowA + i * 16) * 64 + colS1]);
        #pragma unroll
        for (int j = 0; j < 4; j++)
            bf[j] = *reinterpret_cast<const bf16x8*>(&BC[(rowB + j * 16) * 64 + colS1]);
        __builtin_amdgcn_s_barrier();
        __builtin_amdgcn_s_setprio(1);
        #pragma unroll
        for (int i = 0; i < 4; i++)
            #pragma unroll
            for (int j = 0; j < 4; j++)
                acc[i][j] = __builtin_amdgcn_mfma_f32_16x16x32_bf16(af[i], bf[j], acc[i][j], 0, 0, 0);
        __builtin_amdgcn_s_setprio(0);
        __builtin_amdgcn_s_barrier();

        // -------- phase 3: qa=1, ks=1; group boundary --------
        #pragma unroll
        for (int i = 0; i < 4; i++)
            af[i] = *reinterpret_cast<const bf16x8*>(&AC[(rowA + 64 + i * 16) * 64 + colS1]);
        __builtin_amdgcn_s_barrier();
        __builtin_amdgcn_s_setprio(1);
        #pragma unroll
        for (int i = 0; i < 4; i++)
            #pragma unroll
            for (int j = 0; j < 4; j++)
                acc[4 + i][j] = __builtin_amdgcn_mfma_f32_16x16x32_bf16(af[i], bf[j], acc[4 + i][j], 0, 0, 0);
        __builtin_amdgcn_s_setprio(0);
        __builtin_amdgcn_sched_barrier(0);               // pin: nothing sinks past here
        asm volatile("s_waitcnt vmcnt(0)" ::: "memory"); // kt+1 fully in LDS
        __builtin_amdgcn_s_barrier();
    }

    // epilogue: scalar coalesced-by-16-lane stores (same mapping as 128^2 kernel)
    int cr = (l >> 4) * 4;
    #pragma unroll
    for (int ii = 0; ii < 8; ii++) {
        #pragma unroll
        for (int j = 0; j < 4; j++) {
            int col = n0 + wc * 64 + j * 16 + (l & 15);
            #pragma unroll
            for (int rr = 0; rr < 4; rr++) {
                int row = m0 + wr * 128 + ii * 16 + cr + rr;
                C[(size_t)row * N + col] = acc[ii][j][rr];
            }
        }
    }
}

// xc[l,d] = silu(conv_b[l] + sum_k x[l, d+k-1]*conv_w[k,l])   (conv over d!)
__global__ void conv_silu_kernel(const float* __restrict__ xr, const float* __restrict__ cw,
                                 const float* __restrict__ cb, float* __restrict__ xc) {
    int idx = blockIdx.x * 256 + threadIdx.x;
    int l = idx >> 11, d = idx & 2047;
    float acc = cb[l];
    const float* xrow = xr + (size_t)l * 4096;
    #pragma unroll
    for (int k = 0; k < 4; k++) {
        int c = d + k - 1;
        if (c >= 0 && c < DI) acc += xrow[c] * cw[k * SEQ + l];
    }
    xc[idx] = siluf(acc);
}

// fallback xproj (fp32, stride-128 output)
__global__ void xproj_kernel(const float* __restrict__ u, const float* __restrict__ xw,
                             float* __restrict__ xdbl) {
    int l0 = blockIdx.x * 4;
    int t = threadIdx.x; // 128
    __shared__ float us[4][DM];
    for (int i = t; i < 4 * DM; i += 128) us[i >> 10][i & 1023] = u[(size_t)l0 * DM + i];
    __syncthreads();
    if (t < 96) {
        float a0 = 0.f, a1 = 0.f, a2 = 0.f, a3 = 0.f;
        for (int k = 0; k < DM; k++) {
            float wv = xw[(size_t)k * 96 + t];
            a0 += us[0][k] * wv; a1 += us[1][k] * wv;
            a2 += us[2][k] * wv; a3 += us[3][k] * wv;
        }
        xdbl[(size_t)(l0 + 0) * 128 + t] = a0;
        xdbl[(size_t)(l0 + 1) * 128 + t] = a1;
        xdbl[(size_t)(l0 + 2) * 128 + t] = a2;
        xdbl[(size_t)(l0 + 3) * 128 + t] = a3;
    }
}

// ---- chunked selective scan ----
__global__ __launch_bounds__(256) void scan_p1(const float* __restrict__ xc,
        const float* __restrict__ delta, const float* __restrict__ xdbl,
        const float* __restrict__ A_log, float* __restrict__ P, float* __restrict__ S) {
    int c = blockIdx.x;
    int d = blockIdx.y * 256 + threadIdx.x;
    int l0 = c * LC;
    __shared__ float Bsh[LC][16];
    {
        int t = threadIdx.x;   // 256 = LC*16 exactly
        int ll = t >> 4, q = t & 15;
        Bsh[ll][q] = xdbl[(size_t)(l0 + ll) * 128 + 64 + q];
    }
    __syncthreads();
    float a[16];
    #pragma unroll
    for (int i = 0; i < 4; i++) {
        float4 al = ((const float4*)(A_log + (size_t)d * 16))[i];
        a[4*i+0] = -expf(al.x); a[4*i+1] = -expf(al.y);
        a[4*i+2] = -expf(al.z); a[4*i+3] = -expf(al.w);
    }
    float s[16] = {};
    float sumdv = 0.f;
    for (int ll = 0; ll < LC; ll++) {
        float dv = delta[(size_t)(l0 + ll) * DI + d];
        float xv = xc[(size_t)(l0 + ll) * DI + d];
        float du = dv * xv;
        sumdv += dv;
        #pragma unroll
        for (int n = 0; n < 16; n++)
            s[n] = expf(dv * a[n]) * s[n] + du * Bsh[ll][n];
    }
    size_t o = ((size_t)c * DI + d) * 16;
    #pragma unroll
    for (int i = 0; i < 4; i++) {
        float4 sv = make_float4(s[4*i], s[4*i+1], s[4*i+2], s[4*i+3]);
        float4 pv = make_float4(expf(a[4*i]*sumdv), expf(a[4*i+1]*sumdv),
                                expf(a[4*i+2]*sumdv), expf(a[4*i+3]*sumdv));
        ((float4*)(S + o))[i] = sv;
        ((float4*)(P + o))[i] = pv;
    }
}

__global__ void scan_p2(const float* __restrict__ P, const float* __restrict__ S,
                        float* __restrict__ X) {
    int t = blockIdx.x * 256 + threadIdx.x;   // 0 .. DI*16-1
    float x = 0.f;
    #pragma unroll 16
    for (int c = 0; c < NC; c++) {
        X[(size_t)c * (DI*16) + t] = x;
        x = P[(size_t)c * (DI*16) + t] * x + S[(size_t)c * (DI*16) + t];
    }
}

__global__ __launch_bounds__(256) void scan_p3(const float* __restrict__ xc,
        const float* __restrict__ delta, const float* __restrict__ xdbl,
        const float* __restrict__ A_log, const float* __restrict__ Dp,
        const float* __restrict__ X, const float* __restrict__ xr,
        float* __restrict__ y, unsigned short* __restrict__ yb) {
    int c = blockIdx.x;
    int d = blockIdx.y * 256 + threadIdx.x;
    int l0 = c * LC;
    __shared__ float Bsh[LC][16], Csh[LC][16];
    {
        int t = threadIdx.x;
        int ll = t >> 4, q = t & 15;
        size_t row = (size_t)(l0 + ll) * 128;
        Bsh[ll][q] = xdbl[row + 64 + q];
        Csh[ll][q] = xdbl[row + 80 + q];
    }
    __syncthreads();
    float a[16];
    #pragma unroll
    for (int i = 0; i < 4; i++) {
        float4 al = ((const float4*)(A_log + (size_t)d * 16))[i];
        a[4*i+0] = -expf(al.x); a[4*i+1] = -expf(al.y);
        a[4*i+2] = -expf(al.z); a[4*i+3] = -expf(al.w);
    }
    float s[16];
    size_t o = ((size_t)c * DI + d) * 16;
    #pragma unroll
    for (int i = 0; i < 4; i++) {
        float4 xv4 = ((const float4*)(X + o))[i];
        s[4*i] = xv4.x; s[4*i+1] = xv4.y; s[4*i+2] = xv4.z; s[4*i+3] = xv4.w;
    }
    float Dv = Dp[d];
    for (int ll = 0; ll < LC; ll++) {
        size_t lrow = (size_t)(l0 + ll);
        float dv = delta[lrow * DI + d];
        float xv = xc[lrow * DI + d];
        float du = dv * xv;
        float yv = 0.f;
        #pragma unroll
        for (int n = 0; n < 16; n++) {
            s[n] = expf(dv * a[n]) * s[n] + du * Bsh[ll][n];
            yv += s[n] * Csh[ll][n];
        }
        float val = yv + xv * Dv;
        if (yb) {
            float res = xr[lrow * 4096 + 2048 + d];
            yb[lrow * DI + d] = f2bf(val * siluf(res));
        } else {
            y[lrow * DI + d] = val;
        }
    }
}

// fallback: y *= silu(res)
__global__ void ymul_silu(float* __restrict__ y, const float* __restrict__ xr) {
    int idx = blockIdx.x * 256 + threadIdx.x;
    int l = idx >> 11, d = idx & 2047;
    float res = xr[(size_t)l * 4096 + 2048 + d];
    y[idx] = y[idx] * siluf(res);
}

extern "C" void kernel_launch(void* const* d_in, const int* in_sizes, int n_in,
                              void* d_out, int out_size, void* d_ws, size_t ws_size,
                              hipStream_t stream) {
    const int*   ids        = (const int*)d_in[0];
    const float* embed      = (const float*)d_in[1];
    const float* norm_scale = (const float*)d_in[2];
    const float* in_w       = (const float*)d_in[3];
    const float* in_b       = (const float*)d_in[4];
    const float* conv_w     = (const float*)d_in[5];
    const float* conv_b     = (const float*)d_in[6];
    const float* x_proj_w   = (const float*)d_in[7];
    const float* dt_w       = (const float*)d_in[8];
    const float* dt_b       = (const float*)d_in[9];
    const float* out_w      = (const float*)d_in[10];
    const float* out_b      = (const float*)d_in[11];
    const float* A_log      = (const float*)d_in[12];
    const float* Dp         = (const float*)d_in[13];
    const float* norm_f     = (const float*)d_in[14];
    const float* lm_w       = (const float*)d_in[15];

    float* out = (float*)d_out;

    // ---- workspace layout ----
    char* p = (char*)d_ws;
    float* h  = (float*)p;  p += (size_t)SEQ * DM * 4;
    float* hn = (float*)p;  p += (size_t)SEQ * DM * 4;
    size_t base = (size_t)p - (size_t)d_ws;
    const size_t SZ_UB    = (size_t)SEQ * DM * 2;
    const size_t SZ_YB    = (size_t)SEQ * DI * 2;
    const size_t SZ_HNB   = (size_t)SEQ * DM * 2;
    const size_t SZ_DB    = (size_t)SEQ * 64 * 2;
    const size_t SZ_INWT  = (size_t)2 * 4096 * DM * 2;
    const size_t SZ_OUTWT = (size_t)2 * DM * DI * 2;
    const size_t SZ_XPWT  = (size_t)2 * 128 * DM * 2;
    const size_t SZ_DTWT  = (size_t)2 * DI * 64 * 2;
    const size_t SZ_LMWT  = (size_t)NVOC * DM * 2;
    size_t need_mid  = base + SZ_UB + SZ_YB + SZ_HNB + SZ_DB + SZ_INWT + SZ_OUTWT + SZ_XPWT + SZ_DTWT;
    size_t need_full = need_mid + SZ_LMWT;
    bool mid  = ws_size >= need_mid;
    bool full = ws_size >= need_full;

    unsigned short *u_b = nullptr, *y_b = nullptr, *hn_b = nullptr, *dlt_b = nullptr;
    unsigned short *in_wT = nullptr, *out_wT = nullptr, *xp_wT = nullptr, *dt_wT = nullptr, *lm_wT = nullptr;
    if (mid) {
        u_b    = (unsigned short*)p; p += SZ_UB;
        y_b    = (unsigned short*)p; p += SZ_YB;
        hn_b   = (unsigned short*)p; p += SZ_HNB;
        dlt_b  = (unsigned short*)p; p += SZ_DB;
        in_wT  = (unsigned short*)p; p += SZ_INWT;
        out_wT = (unsigned short*)p; p += SZ_OUTWT;
        xp_wT  = (unsigned short*)p; p += SZ_XPWT;
        dt_wT  = (unsigned short*)p; p += SZ_DTWT;
        if (full) { lm_wT = (unsigned short*)p; p += SZ_LMWT; }
    }

    // transient scratch inside d_out (fully rewritten by final GEMM)
    float* u     = out;                          // SEQ*DM (fallback only)
    float* xr    = u + (size_t)SEQ * DM;         // SEQ*4096
    float* xc    = xr + (size_t)SEQ * 4096;      // SEQ*DI
    float* xdbl  = xc + (size_t)SEQ * DI;        // SEQ*128
    float* delta = xdbl + (size_t)SEQ * 128;     // SEQ*DI
    float* y     = delta + (size_t)SEQ * DI;     // SEQ*DI (fallback only)
    float* Pbuf  = y + (size_t)SEQ * DI;         // NC*DI*16
    float* Sbuf  = Pbuf + (size_t)NC * DI * 16;  // NC*DI*16
    float* Xbuf  = Sbuf + (size_t)NC * DI * 16;  // NC*DI*16

    // ---- weight convert+transpose (per call; deterministic) ----
    if (mid) {
        for (int L = 0; L < 2; L++) {
            transpose_f2bf<<<dim3(4096 / 32, DM / 32), dim3(32, 8), 0, stream>>>(
                in_w + (size_t)L * DM * 4096, in_wT + (size_t)L * 4096 * DM, DM, 4096);
            transpose_f2bf<<<dim3(DM / 32, DI / 32), dim3(32, 8), 0, stream>>>(
                out_w + (size_t)L * DI * DM, out_wT + (size_t)L * DM * DI, DI, DM);
            transpose_f2bf<<<dim3(128 / 32, DM / 32), dim3(32, 8), 0, stream>>>(
                x_proj_w + (size_t)L * DM * 96, xp_wT + (size_t)L * 128 * DM, DM, 96);
            transpose_f2bf<<<dim3(DI / 32, 64 / 32), dim3(32, 8), 0, stream>>>(
                dt_w + (size_t)L * DTR * DI, dt_wT + (size_t)L * DI * 64, DTR, DI);
        }
        if (full)
            transpose_f2bf<<<dim3(NVOC / 32, DM / 32), dim3(32, 8), 0, stream>>>(
                lm_w, lm_wT, DM, NVOC);
    }

    embed_gather<<<SEQ, 256, 0, stream>>>(ids, embed, h);

    for (int L = 0; L < 2; L++) {
        rmsnorm_kernel<<<SEQ, 256, 0, stream>>>(h, norm_scale + (size_t)L * DM, u, u_b);
        if (mid) {
            gemm_bf16<1, 0, 0, 0><<<dim3(SEQ / 128, 4096 / 128), 256, 0, stream>>>(
                u_b, DM, in_wT + (size_t)L * 4096 * DM, in_b + (size_t)L * 4096, nullptr, xr,
                nullptr, SEQ, 4096, DM);
        } else {
            gemm_f32<0><<<dim3(4096 / 64, SEQ / 64), dim3(16, 16), 0, stream>>>(
                u, DM, in_w + (size_t)L * DM * 4096, in_b + (size_t)L * 4096, nullptr, xr,
                SEQ, 4096, DM);
        }
        conv_silu_kernel<<<SEQ * DI / 256, 256, 0, stream>>>(
            xr, conv_w + (size_t)L * 4 * SEQ, conv_b + (size_t)L * SEQ, xc);
        if (mid) {
            gemm_bf16<0, 0, 0, 1><<<dim3(SEQ / 128, 1), 256, 0, stream>>>(
                u_b, DM, xp_wT + (size_t)L * 128 * DM, nullptr, nullptr, xdbl,
                dlt_b, SEQ, 128, DM);
            gemm_bf16<1, 0, 1, 0><<<dim3(SEQ / 128, DI / 128), 256, 0, stream>>>(
                dlt_b, 64, dt_wT + (size_t)L * DI * 64, dt_b + (size_t)L * DI, nullptr, delta,
                nullptr, SEQ, DI, 64);
        } else {
            xproj_kernel<<<SEQ / 4, 128, 0, stream>>>(u, x_proj_w + (size_t)L * DM * 96, xdbl);
            gemm_f32<1><<<dim3(DI / 64, SEQ / 64), dim3(16, 16), 0, stream>>>(
                xdbl, 128, dt_w + (size_t)L * DTR * DI, dt_b + (size_t)L * DI, nullptr, delta,
                SEQ, DI, DTR);
        }
        scan_p1<<<dim3(NC, DI / 256), 256, 0, stream>>>(
            xc, delta, xdbl, A_log + (size_t)L * DI * DST, Pbuf, Sbuf);
        scan_p2<<<DI * 16 / 256, 256, 0, stream>>>(Pbuf, Sbuf, Xbuf);
        scan_p3<<<dim3(NC, DI / 256), 256, 0, stream>>>(
            xc, delta, xdbl, A_log + (size_t)L * DI * DST, Dp + (size_t)L * DI, Xbuf, xr,
            y, y_b);
        if (mid) {
            gemm_bf16<1, 1, 0, 0><<<dim3(SEQ / 128, DM / 128), 256, 0, stream>>>(
                y_b, DI, out_wT + (size_t)L * DM * DI, out_b + (size_t)L * DM, h, h,
                nullptr, SEQ, DM, DI);
        } else {
            ymul_silu<<<SEQ * DI / 256, 256, 0, stream>>>(y, xr);
            gemm_f32<0><<<dim3(DM / 64, SEQ / 64), dim3(16, 16), 0, stream>>>(
                y, DI, out_w + (size_t)L * DI * DM, out_b + (size_t)L * DM, h, h,
                SEQ, DM, DI);
        }
    }

    rmsnorm_kernel<<<SEQ, 256, 0, stream>>>(h, norm_f, hn, full ? hn_b : nullptr);
    if (full) {
        hipFuncSetAttribute((const void*)gemm_bf16_8ph,
                            hipFuncAttributeMaxDynamicSharedMemorySize, 131072);
        gemm_bf16_8ph<<<dim3(SEQ / 256, NVOC / 256), 512, 131072, stream>>>(
            hn_b, lm_wT, out, SEQ, NVOC, DM);
    } else {
        gemm_f32<0><<<dim3(NVOC / 64, SEQ / 64), dim3(16, 16), 0, stream>>>(
            hn, DM, lm_w, nullptr, nullptr, out, SEQ, NVOC, DM);
    }
}

// Round 7
// 837.080 us; speedup vs baseline: 1.1645x; 1.0358x over previous
//
#include <hip/hip_runtime.h>
#include <hip/hip_bf16.h>

#define SEQ 2048
#define DM  1024
#define DI  2048
#define DST 16
#define DTR 64
#define NVOC 32000
#define NVOCP 32768   // padded N for lm_head 8-phase grid (128 tiles of 256)
#define NC  128   // scan chunks
#define LC  16    // chunk length; NC*LC == SEQ

typedef __bf16 bf16x8 __attribute__((ext_vector_type(8)));
typedef float  f32x4  __attribute__((ext_vector_type(4)));

__device__ __forceinline__ float siluf(float x) { return x / (1.f + expf(-x)); }
__device__ __forceinline__ float softplusf(float x) {
    return fmaxf(x, 0.f) + log1pf(expf(-fabsf(x)));
}
__device__ __forceinline__ unsigned short f2bf(float f) {
    union { __hip_bfloat16 h; unsigned short u; } c;
    c.h = __float2bfloat16(f);
    return c.u;
}

// h[l,:] = embed[ids[l],:]
__global__ void embed_gather(const int* __restrict__ ids, const float* __restrict__ embed,
                             float* __restrict__ h) {
    int l = blockIdx.x;
    int row = ids[l];
    const float4* src = (const float4*)(embed + (size_t)row * DM);
    float4* dst = (float4*)(h + (size_t)l * DM);
    dst[threadIdx.x] = src[threadIdx.x];
}

// o[l,:] = x[l,:]*rsqrt(mean(x^2)+eps)*w[:]
// If ob != nullptr: write ONLY bf16 (f32 skipped). Else write f32.
__global__ void rmsnorm_kernel(const float* __restrict__ x, const float* __restrict__ w,
                               float* __restrict__ o, unsigned short* __restrict__ ob) {
    int l = blockIdx.x;
    int t = threadIdx.x; // 256
    float4 v = ((const float4*)(x + (size_t)l * DM))[t];
    float ss = v.x*v.x + v.y*v.y + v.z*v.z + v.w*v.w;
    #pragma unroll
    for (int m = 32; m; m >>= 1) ss += __shfl_xor(ss, m);
    __shared__ float red[4];
    if ((t & 63) == 0) red[t >> 6] = ss;
    __syncthreads();
    float tot = red[0] + red[1] + red[2] + red[3];
    float sc = rsqrtf(tot * (1.f / DM) + 1e-6f);
    float4 wv = ((const float4*)w)[t];
    float4 ov;
    ov.x = v.x * sc * wv.x;
    ov.y = v.y * sc * wv.y;
    ov.z = v.z * sc * wv.z;
    ov.w = v.w * sc * wv.w;
    if (ob) {
        uint2 pk;
        pk.x = (unsigned)f2bf(ov.x) | ((unsigned)f2bf(ov.y) << 16);
        pk.y = (unsigned)f2bf(ov.z) | ((unsigned)f2bf(ov.w) << 16);
        ((uint2*)(ob + (size_t)l * DM))[t] = pk;
    } else {
        ((float4*)(o + (size_t)l * DM))[t] = ov;
    }
}

// W fp32 [K][N] -> WT bf16 [Npad][K]; rows n>=N zero-filled
__global__ void transpose_f2bf(const float* __restrict__ W, unsigned short* __restrict__ WT,
                               int K, int N) {
    __shared__ float tile[32][33];
    int k0 = blockIdx.y * 32, n0 = blockIdx.x * 32;
    int tx = threadIdx.x;  // 32
    int ty = threadIdx.y;  // 8
    #pragma unroll
    for (int i = 0; i < 32; i += 8) {
        int n = n0 + tx;
        tile[ty + i][tx] = (n < N) ? W[(size_t)(k0 + ty + i) * N + n] : 0.f;
    }
    __syncthreads();
    #pragma unroll
    for (int i = 0; i < 32; i += 8)
        WT[(size_t)(n0 + ty + i) * K + k0 + tx] = f2bf(tile[tx][ty + i]);
}

// Generic fp32 GEMM (fallback only)
template<int ACT>
__global__ __launch_bounds__(256) void gemm_f32(const float* __restrict__ A, int lda,
                                                const float* __restrict__ B,
                                                const float* __restrict__ bias,
                                                const float* __restrict__ add,
                                                float* __restrict__ C,
                                                int M, int N, int K) {
    __shared__ float As[16][68];
    __shared__ float Bs[16][64];
    int tx = threadIdx.x, ty = threadIdx.y;
    int t = ty * 16 + tx;
    int m0 = blockIdx.y * 64, n0 = blockIdx.x * 64;
    float acc[4][4] = {};
    for (int k0 = 0; k0 < K; k0 += 16) {
        #pragma unroll
        for (int i = 0; i < 4; i++) {
            int idx = t + i * 256;
            int mm = idx >> 4, kk = idx & 15;
            As[kk][mm] = A[(size_t)(m0 + mm) * lda + k0 + kk];
            int nn = idx & 63, k2 = idx >> 6;
            Bs[k2][nn] = B[(size_t)(k0 + k2) * N + n0 + nn];
        }
        __syncthreads();
        #pragma unroll
        for (int kk = 0; kk < 16; kk++) {
            float4 a = *(const float4*)&As[kk][ty * 4];
            float4 b = *(const float4*)&Bs[kk][tx * 4];
            acc[0][0] += a.x*b.x; acc[0][1] += a.x*b.y; acc[0][2] += a.x*b.z; acc[0][3] += a.x*b.w;
            acc[1][0] += a.y*b.x; acc[1][1] += a.y*b.y; acc[1][2] += a.y*b.z; acc[1][3] += a.y*b.w;
            acc[2][0] += a.z*b.x; acc[2][1] += a.z*b.y; acc[2][2] += a.z*b.z; acc[2][3] += a.z*b.w;
            acc[3][0] += a.w*b.x; acc[3][1] += a.w*b.y; acc[3][2] += a.w*b.z; acc[3][3] += a.w*b.w;
        }
        __syncthreads();
    }
    #pragma unroll
    for (int i = 0; i < 4; i++) {
        int row = m0 + ty * 4 + i;
        float4 r;
        float* pr = &r.x;
        #pragma unroll
        for (int j = 0; j < 4; j++) {
            int col = n0 + tx * 4 + j;
            float v = acc[i][j];
            if (bias) v += bias[col];
            if (add)  v += add[(size_t)row * N + col];
            if (ACT == 1) v = softplusf(v);
            pr[j] = v;
        }
        *(float4*)&C[(size_t)row * N + n0 + tx * 4] = r;
    }
}

// bf16 MFMA GEMM (R3-proven m97 structure): C(MxN,f32) = A(bf16 [M][lda]) @ BT(bf16 [N][K])^T
// 128x128 tile, BK=32, 256 threads = 4 waves (2x2), 4x4 fragments of 16x16x32.
// XP: blocks with n0>=4096 write xp_out[row*128 + (col-4096)] (f32, no bias) and
//     aux[row*64 + c2] bf16 for c2<64; normal blocks use ldc=4096.
template<int BIAS, int ADD, int ACT, int XP>
__global__ __launch_bounds__(256) void gemm_bf16(const unsigned short* __restrict__ A, int lda,
                                                 const unsigned short* __restrict__ BT,
                                                 const float* __restrict__ bias,
                                                 const float* __restrict__ add,
                                                 float* __restrict__ C,
                                                 float* __restrict__ xp_out,
                                                 unsigned short* __restrict__ aux,
                                                 int M, int N, int K) {
    __shared__ unsigned short As[128 * 32];
    __shared__ unsigned short Bs[128 * 32];
    int t = threadIdx.x;
    int w = t >> 6, l = t & 63;
    int wm = w >> 1, wn = w & 1;
    int m0 = blockIdx.x * 128;
    int n0 = blockIdx.y * 128;
    int lr = l & 15, lk = (l >> 4) * 8;
    int sr = t >> 2, sc = (t & 3) * 8;     // staging: row, k-offset
    f32x4 acc[4][4] = {};
    for (int k0 = 0; k0 < K; k0 += 32) {
        const unsigned short* ga = A  + (size_t)(m0 + sr) * lda + k0 + sc;
        const unsigned short* gb = BT + (size_t)(n0 + sr) * K + k0 + sc;
        unsigned short* la = As + w * 512;   // wave-uniform base; HW adds lane*16B
        unsigned short* lb = Bs + w * 512;
        __builtin_amdgcn_global_load_lds((const __attribute__((address_space(1))) void*)ga,
            (__attribute__((address_space(3))) void*)la, 16, 0, 0);
        __builtin_amdgcn_global_load_lds((const __attribute__((address_space(1))) void*)(ga + (size_t)64 * lda),
            (__attribute__((address_space(3))) void*)(la + 2048), 16, 0, 0);
        __builtin_amdgcn_global_load_lds((const __attribute__((address_space(1))) void*)gb,
            (__attribute__((address_space(3))) void*)(lb), 16, 0, 0);
        __builtin_amdgcn_global_load_lds((const __attribute__((address_space(1))) void*)(gb + (size_t)64 * K),
            (__attribute__((address_space(3))) void*)(lb + 2048), 16, 0, 0);
        __syncthreads();
        bf16x8 af[4], bfr[4];
        #pragma unroll
        for (int i = 0; i < 4; i++) {
            af[i]  = *reinterpret_cast<const bf16x8*>(&As[(wm * 64 + i * 16 + lr) * 32 + lk]);
            bfr[i] = *reinterpret_cast<const bf16x8*>(&Bs[(wn * 64 + i * 16 + lr) * 32 + lk]);
        }
        #pragma unroll
        for (int i = 0; i < 4; i++)
            #pragma unroll
            for (int j = 0; j < 4; j++)
                acc[i][j] = __builtin_amdgcn_mfma_f32_16x16x32_bf16(af[i], bfr[j], acc[i][j], 0, 0, 0);
        __syncthreads();
    }
    int cr = (l >> 4) * 4;
    if (XP && n0 >= 4096) {
        // xproj region: cols 4096..4223 -> xdbl stride 128 (+ bf16 delta cols 0..63)
        #pragma unroll
        for (int i = 0; i < 4; i++) {
            #pragma unroll
            for (int j = 0; j < 4; j++) {
                int c2 = (n0 - 4096) + wn * 64 + j * 16 + lr;
                #pragma unroll
                for (int rr = 0; rr < 4; rr++) {
                    int row = m0 + wm * 64 + i * 16 + cr + rr;
                    float v = acc[i][j][rr];
                    xp_out[(size_t)row * 128 + c2] = v;
                    if (c2 < 64) aux[(size_t)row * 64 + c2] = f2bf(v);
                }
            }
        }
    } else {
        int ldc = XP ? 4096 : N;
        #pragma unroll
        for (int i = 0; i < 4; i++) {
            #pragma unroll
            for (int j = 0; j < 4; j++) {
                int col = n0 + wn * 64 + j * 16 + lr;
                float bv = BIAS ? bias[col] : 0.f;
                #pragma unroll
                for (int rr = 0; rr < 4; rr++) {
                    int row = m0 + wm * 64 + i * 16 + cr + rr;
                    float v = acc[i][j][rr] + bv;
                    if (ADD) v += add[(size_t)row * ldc + col];
                    if (ACT == 1) v = softplusf(v);
                    C[(size_t)row * ldc + col] = v;
                }
            }
        }
    }
}

// ============ 256x256 8-phase bf16 GEMM (T2 swizzle + T3/T4 + T5) ============
// C(MxN,f32) = A(bf16 [M][K]) @ BT(bf16 [N][K])^T, stores guarded col<N.
// XCD-locality mapping (requires gridDim.x==8, gridDim.y%8==0): each XCD owns
// gridDim.y/8 contiguous N-panels; the 8 M-blocks of a panel are co-resident.
__global__ __launch_bounds__(512, 1) void gemm_bf16_8ph(
        const unsigned short* __restrict__ A,
        const unsigned short* __restrict__ BT,
        float* __restrict__ C, int M, int N, int K) {
    extern __shared__ unsigned short lds[];   // [A0|A1|B0|B1] x 16384 shorts
    const int t = threadIdx.x;
    const int w = t >> 6, l = t & 63;
    const int wr = w >> 2, wc = w & 3;
    int bxx = blockIdx.x, byy = blockIdx.y;
    if (gridDim.x == 8 && (gridDim.y & 7) == 0) {
        int lin = blockIdx.y * 8 + blockIdx.x;
        int xcd = lin & 7, i = lin >> 3;
        bxx = i & 7;
        byy = xcd * (gridDim.y >> 3) + (i >> 3);
    }
    const int m0 = bxx * 256, n0 = byy * 256;
    const int lane8 = l >> 3, lane7 = l & 7;
    const int swz = (lane7 ^ lane8) * 8;                  // staging k-offset (elements)
    const int colS0 = ((l >> 4) * 8) ^ (lane7 << 3);      // ds_read col (shorts), ks=0
    const int colS1 = (32 + ((l >> 4) * 8)) ^ (lane7 << 3); // ks=1
    const int rowA = wr * 128 + (l & 15);
    const int rowB = wc * 64 + (l & 15);
    const int srow = w * 8 + lane8;                       // staging row (+q*64)
    const int NT = K >> 6;
    f32x4 acc[8][4] = {};
    bf16x8 af[4], bf[4];

    // prologue: stage K-tile 0 into buf0 (A halves + B halves, 8 loads)
    {
        const unsigned short* a0 = A + (size_t)(m0 + srow) * K + swz;
        const unsigned short* b0 = BT + (size_t)(n0 + srow) * K + swz;
        #pragma unroll
        for (int q = 0; q < 4; q++) {
            __builtin_amdgcn_global_load_lds(
                (const __attribute__((address_space(1))) void*)(a0 + (size_t)q * 64 * K),
                (__attribute__((address_space(3))) void*)(lds + q * 4096 + w * 512), 16, 0, 0);
            __builtin_amdgcn_global_load_lds(
                (const __attribute__((address_space(1))) void*)(b0 + (size_t)q * 64 * K),
                (__attribute__((address_space(3))) void*)(lds + 32768 + q * 4096 + w * 512), 16, 0, 0);
        }
        asm volatile("s_waitcnt vmcnt(0)" ::: "memory");
        __builtin_amdgcn_s_barrier();
    }

    for (int kt = 0; kt < NT; kt++) {
        const unsigned short* AC = lds + (kt & 1) * 16384;
        const unsigned short* BC = lds + 32768 + (kt & 1) * 16384;
        unsigned short* AN = lds + ((kt & 1) ^ 1) * 16384;
        unsigned short* BN = lds + 32768 + ((kt & 1) ^ 1) * 16384;
        const bool st = (kt + 1 < NT);
        const unsigned short* aS = A + (size_t)(m0 + srow) * K + ((kt + 1) << 6) + swz;
        const unsigned short* bS = BT + (size_t)(n0 + srow) * K + ((kt + 1) << 6) + swz;

        // -------- phase 0: qa=0, ks=0; stage A(kt+1) both halves --------
        #pragma unroll
        for (int i = 0; i < 4; i++)
            af[i] = *reinterpret_cast<const bf16x8*>(&AC[(rowA + i * 16) * 64 + colS0]);
        #pragma unroll
        for (int j = 0; j < 4; j++)
            bf[j] = *reinterpret_cast<const bf16x8*>(&BC[(rowB + j * 16) * 64 + colS0]);
        if (st) {
            #pragma unroll
            for (int q = 0; q < 4; q++)
                __builtin_amdgcn_global_load_lds(
                    (const __attribute__((address_space(1))) void*)(aS + (size_t)q * 64 * K),
                    (__attribute__((address_space(3))) void*)(AN + q * 4096 + w * 512), 16, 0, 0);
        }
        __builtin_amdgcn_s_barrier();
        __builtin_amdgcn_s_setprio(1);
        #pragma unroll
        for (int i = 0; i < 4; i++)
            #pragma unroll
            for (int j = 0; j < 4; j++)
                acc[i][j] = __builtin_amdgcn_mfma_f32_16x16x32_bf16(af[i], bf[j], acc[i][j], 0, 0, 0);
        __builtin_amdgcn_s_setprio(0);
        __builtin_amdgcn_s_barrier();

        // -------- phase 1: qa=1, ks=0; stage B(kt+1) both halves --------
        #pragma unroll
        for (int i = 0; i < 4; i++)
            af[i] = *reinterpret_cast<const bf16x8*>(&AC[(rowA + 64 + i * 16) * 64 + colS0]);
        if (st) {
            #pragma unroll
            for (int q = 0; q < 4; q++)
                __builtin_amdgcn_global_load_lds(
                    (const __attribute__((address_space(1))) void*)(bS + (size_t)q * 64 * K),
                    (__attribute__((address_space(3))) void*)(BN + q * 4096 + w * 512), 16, 0, 0);
        }
        __builtin_amdgcn_s_barrier();
        __builtin_amdgcn_s_setprio(1);
        #pragma unroll
        for (int i = 0; i < 4; i++)
            #pragma unroll
            for (int j = 0; j < 4; j++)
                acc[4 + i][j] = __builtin_amdgcn_mfma_f32_16x16x32_bf16(af[i], bf[j], acc[4 + i][j], 0, 0, 0);
        __builtin_amdgcn_s_setprio(0);
        __builtin_amdgcn_s_barrier();

        // -------- phase 2: qa=0, ks=1 --------
        #pragma unroll
        for (int i = 0; i < 4; i++)
            af[i] = *reinterpret_cast<const bf16x8*>(&AC[(rowA + i * 16) * 64 + colS1]);
        #pragma unroll
        for (int j = 0; j < 4; j++)
            bf[j] = *reinterpret_cast<const bf16x8*>(&BC[(rowB + j * 16) * 64 + colS1]);
        __builtin_amdgcn_s_barrier();
        __builtin_amdgcn_s_setprio(1);
        #pragma unroll
        for (int i = 0; i < 4; i++)
            #pragma unroll
            for (int j = 0; j < 4; j++)
                acc[i][j] = __builtin_amdgcn_mfma_f32_16x16x32_bf16(af[i], bf[j], acc[i][j], 0, 0, 0);
        __builtin_amdgcn_s_setprio(0);
        __builtin_amdgcn_s_barrier();

        // -------- phase 3: qa=1, ks=1; group boundary --------
        #pragma unroll
        for (int i = 0; i < 4; i++)
            af[i] = *reinterpret_cast<const bf16x8*>(&AC[(rowA + 64 + i * 16) * 64 + colS1]);
        __builtin_amdgcn_s_barrier();
        __builtin_amdgcn_s_setprio(1);
        #pragma unroll
        for (int i = 0; i < 4; i++)
            #pragma unroll
            for (int j = 0; j < 4; j++)
                acc[4 + i][j] = __builtin_amdgcn_mfma_f32_16x16x32_bf16(af[i], bf[j], acc[4 + i][j], 0, 0, 0);
        __builtin_amdgcn_s_setprio(0);
        __builtin_amdgcn_sched_barrier(0);               // pin: nothing sinks past here
        asm volatile("s_waitcnt vmcnt(0)" ::: "memory"); // kt+1 fully in LDS
        __builtin_amdgcn_s_barrier();
    }

    // epilogue: stores guarded col<N (grid may be padded past N)
    int cr = (l >> 4) * 4;
    #pragma unroll
    for (int ii = 0; ii < 8; ii++) {
        #pragma unroll
        for (int j = 0; j < 4; j++) {
            int col = n0 + wc * 64 + j * 16 + (l & 15);
            if (col < N) {
                #pragma unroll
                for (int rr = 0; rr < 4; rr++) {
                    int row = m0 + wr * 128 + ii * 16 + cr + rr;
                    C[(size_t)row * N + col] = acc[ii][j][rr];
                }
            }
        }
    }
}

// xc[l,d] = silu(conv_b[l] + sum_k x[l, d+k-1]*conv_w[k,l])   (conv over d!)
__global__ void conv_silu_kernel(const float* __restrict__ xr, const float* __restrict__ cw,
                                 const float* __restrict__ cb, float* __restrict__ xc) {
    int idx = blockIdx.x * 256 + threadIdx.x;
    int l = idx >> 11, d = idx & 2047;
    float acc = cb[l];
    const float* xrow = xr + (size_t)l * 4096;
    #pragma unroll
    for (int k = 0; k < 4; k++) {
        int c = d + k - 1;
        if (c >= 0 && c < DI) acc += xrow[c] * cw[k * SEQ + l];
    }
    xc[idx] = siluf(acc);
}

// fallback xproj (fp32, stride-128 output)
__global__ void xproj_kernel(const float* __restrict__ u, const float* __restrict__ xw,
                             float* __restrict__ xdbl) {
    int l0 = blockIdx.x * 4;
    int t = threadIdx.x; // 128
    __shared__ float us[4][DM];
    for (int i = t; i < 4 * DM; i += 128) us[i >> 10][i & 1023] = u[(size_t)l0 * DM + i];
    __syncthreads();
    if (t < 96) {
        float a0 = 0.f, a1 = 0.f, a2 = 0.f, a3 = 0.f;
        for (int k = 0; k < DM; k++) {
            float wv = xw[(size_t)k * 96 + t];
            a0 += us[0][k] * wv; a1 += us[1][k] * wv;
            a2 += us[2][k] * wv; a3 += us[3][k] * wv;
        }
        xdbl[(size_t)(l0 + 0) * 128 + t] = a0;
        xdbl[(size_t)(l0 + 1) * 128 + t] = a1;
        xdbl[(size_t)(l0 + 2) * 128 + t] = a2;
        xdbl[(size_t)(l0 + 3) * 128 + t] = a3;
    }
}

// ---- chunked selective scan ----
__global__ __launch_bounds__(256) void scan_p1(const float* __restrict__ xc,
        const float* __restrict__ delta, const float* __restrict__ xdbl,
        const float* __restrict__ A_log, float* __restrict__ P, float* __restrict__ S) {
    int c = blockIdx.x;
    int d = blockIdx.y * 256 + threadIdx.x;
    int l0 = c * LC;
    __shared__ float Bsh[LC][16];
    {
        int t = threadIdx.x;   // 256 = LC*16 exactly
        int ll = t >> 4, q = t & 15;
        Bsh[ll][q] = xdbl[(size_t)(l0 + ll) * 128 + 64 + q];
    }
    __syncthreads();
    float a[16];
    #pragma unroll
    for (int i = 0; i < 4; i++) {
        float4 al = ((const float4*)(A_log + (size_t)d * 16))[i];
        a[4*i+0] = -expf(al.x); a[4*i+1] = -expf(al.y);
        a[4*i+2] = -expf(al.z); a[4*i+3] = -expf(al.w);
    }
    float s[16] = {};
    float sumdv = 0.f;
    for (int ll = 0; ll < LC; ll++) {
        float dv = delta[(size_t)(l0 + ll) * DI + d];
        float xv = xc[(size_t)(l0 + ll) * DI + d];
        float du = dv * xv;
        sumdv += dv;
        #pragma unroll
        for (int n = 0; n < 16; n++)
            s[n] = expf(dv * a[n]) * s[n] + du * Bsh[ll][n];
    }
    size_t o = ((size_t)c * DI + d) * 16;
    #pragma unroll
    for (int i = 0; i < 4; i++) {
        float4 sv = make_float4(s[4*i], s[4*i+1], s[4*i+2], s[4*i+3]);
        float4 pv = make_float4(expf(a[4*i]*sumdv), expf(a[4*i+1]*sumdv),
                                expf(a[4*i+2]*sumdv), expf(a[4*i+3]*sumdv));
        ((float4*)(S + o))[i] = sv;
        ((float4*)(P + o))[i] = pv;
    }
}

__global__ void scan_p2(const float* __restrict__ P, const float* __restrict__ S,
                        float* __restrict__ X) {
    int t = blockIdx.x * 256 + threadIdx.x;   // 0 .. DI*16-1
    float x = 0.f;
    #pragma unroll 16
    for (int c = 0; c < NC; c++) {
        X[(size_t)c * (DI*16) + t] = x;
        x = P[(size_t)c * (DI*16) + t] * x + S[(size_t)c * (DI*16) + t];
    }
}

__global__ __launch_bounds__(256) void scan_p3(const float* __restrict__ xc,
        const float* __restrict__ delta, const float* __restrict__ xdbl,
        const float* __restrict__ A_log, const float* __restrict__ Dp,
        const float* __restrict__ X, const float* __restrict__ xr,
        float* __restrict__ y, unsigned short* __restrict__ yb) {
    int c = blockIdx.x;
    int d = blockIdx.y * 256 + threadIdx.x;
    int l0 = c * LC;
    __shared__ float Bsh[LC][16], Csh[LC][16];
    {
        int t = threadIdx.x;
        int ll = t >> 4, q = t & 15;
        size_t row = (size_t)(l0 + ll) * 128;
        Bsh[ll][q] = xdbl[row + 64 + q];
        Csh[ll][q] = xdbl[row + 80 + q];
    }
    __syncthreads();
    float a[16];
    #pragma unroll
    for (int i = 0; i < 4; i++) {
        float4 al = ((const float4*)(A_log + (size_t)d * 16))[i];
        a[4*i+0] = -expf(al.x); a[4*i+1] = -expf(al.y);
        a[4*i+2] = -expf(al.z); a[4*i+3] = -expf(al.w);
    }
    float s[16];
    size_t o = ((size_t)c * DI + d) * 16;
    #pragma unroll
    for (int i = 0; i < 4; i++) {
        float4 xv4 = ((const float4*)(X + o))[i];
        s[4*i] = xv4.x; s[4*i+1] = xv4.y; s[4*i+2] = xv4.z; s[4*i+3] = xv4.w;
    }
    float Dv = Dp[d];
    for (int ll = 0; ll < LC; ll++) {
        size_t lrow = (size_t)(l0 + ll);
        float dv = delta[lrow * DI + d];
        float xv = xc[lrow * DI + d];
        float du = dv * xv;
        float yv = 0.f;
        #pragma unroll
        for (int n = 0; n < 16; n++) {
            s[n] = expf(dv * a[n]) * s[n] + du * Bsh[ll][n];
            yv += s[n] * Csh[ll][n];
        }
        float val = yv + xv * Dv;
        if (yb) {
            float res = xr[lrow * 4096 + 2048 + d];
            yb[lrow * DI + d] = f2bf(val * siluf(res));
        } else {
            y[lrow * DI + d] = val;
        }
    }
}

// fallback: y *= silu(res)
__global__ void ymul_silu(float* __restrict__ y, const float* __restrict__ xr) {
    int idx = blockIdx.x * 256 + threadIdx.x;
    int l = idx >> 11, d = idx & 2047;
    float res = xr[(size_t)l * 4096 + 2048 + d];
    y[idx] = y[idx] * siluf(res);
}

extern "C" void kernel_launch(void* const* d_in, const int* in_sizes, int n_in,
                              void* d_out, int out_size, void* d_ws, size_t ws_size,
                              hipStream_t stream) {
    const int*   ids        = (const int*)d_in[0];
    const float* embed      = (const float*)d_in[1];
    const float* norm_scale = (const float*)d_in[2];
    const float* in_w       = (const float*)d_in[3];
    const float* in_b       = (const float*)d_in[4];
    const float* conv_w     = (const float*)d_in[5];
    const float* conv_b     = (const float*)d_in[6];
    const float* x_proj_w   = (const float*)d_in[7];
    const float* dt_w       = (const float*)d_in[8];
    const float* dt_b       = (const float*)d_in[9];
    const float* out_w      = (const float*)d_in[10];
    const float* out_b      = (const float*)d_in[11];
    const float* A_log      = (const float*)d_in[12];
    const float* Dp         = (const float*)d_in[13];
    const float* norm_f     = (const float*)d_in[14];
    const float* lm_w       = (const float*)d_in[15];

    float* out = (float*)d_out;

    // ---- workspace layout ----
    char* p = (char*)d_ws;
    float* h  = (float*)p;  p += (size_t)SEQ * DM * 4;
    float* hn = (float*)p;  p += (size_t)SEQ * DM * 4;
    size_t base = (size_t)p - (size_t)d_ws;
    const size_t SZ_UB    = (size_t)SEQ * DM * 2;
    const size_t SZ_YB    = (size_t)SEQ * DI * 2;
    const size_t SZ_HNB   = (size_t)SEQ * DM * 2;
    const size_t SZ_DB    = (size_t)SEQ * 64 * 2;
    const size_t SZ_INWT  = (size_t)2 * 4224 * DM * 2;   // in_proj(4096) + xproj(128) rows
    const size_t SZ_OUTWT = (size_t)2 * DM * DI * 2;
    const size_t SZ_DTWT  = (size_t)2 * DI * 64 * 2;
    const size_t SZ_LMWT  = (size_t)NVOCP * DM * 2;      // padded to 32768 rows
    size_t need_mid  = base + SZ_UB + SZ_YB + SZ_HNB + SZ_DB + SZ_INWT + SZ_OUTWT + SZ_DTWT;
    size_t need_full = need_mid + SZ_LMWT;
    bool mid  = ws_size >= need_mid;
    bool full = ws_size >= need_full;

    unsigned short *u_b = nullptr, *y_b = nullptr, *hn_b = nullptr, *dlt_b = nullptr;
    unsigned short *in_wT = nullptr, *out_wT = nullptr, *dt_wT = nullptr, *lm_wT = nullptr;
    if (mid) {
        u_b    = (unsigned short*)p; p += SZ_UB;
        y_b    = (unsigned short*)p; p += SZ_YB;
        hn_b   = (unsigned short*)p; p += SZ_HNB;
        dlt_b  = (unsigned short*)p; p += SZ_DB;
        in_wT  = (unsigned short*)p; p += SZ_INWT;
        out_wT = (unsigned short*)p; p += SZ_OUTWT;
        dt_wT  = (unsigned short*)p; p += SZ_DTWT;
        if (full) { lm_wT = (unsigned short*)p; p += SZ_LMWT; }
    }

    // transient scratch inside d_out (fully rewritten by final GEMM)
    float* u     = out;                          // SEQ*DM (fallback only)
    float* xr    = u + (size_t)SEQ * DM;         // SEQ*4096
    float* xc    = xr + (size_t)SEQ * 4096;      // SEQ*DI
    float* xdbl  = xc + (size_t)SEQ * DI;        // SEQ*128
    float* delta = xdbl + (size_t)SEQ * 128;     // SEQ*DI
    float* y     = delta + (size_t)SEQ * DI;     // SEQ*DI (fallback only)
    float* Pbuf  = y + (size_t)SEQ * DI;         // NC*DI*16
    float* Sbuf  = Pbuf + (size_t)NC * DI * 16;  // NC*DI*16
    float* Xbuf  = Sbuf + (size_t)NC * DI * 16;  // NC*DI*16

    // ---- weight convert+transpose (per call; deterministic) ----
    if (mid) {
        for (int L = 0; L < 2; L++) {
            transpose_f2bf<<<dim3(4096 / 32, DM / 32), dim3(32, 8), 0, stream>>>(
                in_w + (size_t)L * DM * 4096, in_wT + (size_t)L * 4224 * DM, DM, 4096);
            transpose_f2bf<<<dim3(128 / 32, DM / 32), dim3(32, 8), 0, stream>>>(
                x_proj_w + (size_t)L * DM * 96, in_wT + (size_t)L * 4224 * DM + (size_t)4096 * DM, DM, 96);
            transpose_f2bf<<<dim3(DM / 32, DI / 32), dim3(32, 8), 0, stream>>>(
                out_w + (size_t)L * DI * DM, out_wT + (size_t)L * DM * DI, DI, DM);
            transpose_f2bf<<<dim3(DI / 32, 64 / 32), dim3(32, 8), 0, stream>>>(
                dt_w + (size_t)L * DTR * DI, dt_wT + (size_t)L * DI * 64, DTR, DI);
        }
        if (full)
            transpose_f2bf<<<dim3(NVOCP / 32, DM / 32), dim3(32, 8), 0, stream>>>(
                lm_w, lm_wT, DM, NVOC);
    }

    embed_gather<<<SEQ, 256, 0, stream>>>(ids, embed, h);

    for (int L = 0; L < 2; L++) {
        rmsnorm_kernel<<<SEQ, 256, 0, stream>>>(h, norm_scale + (size_t)L * DM, u, u_b);
        if (mid) {
            // fused in_proj + xproj: N = 4224 (33 tiles); cols>=4096 -> xdbl/dlt_b
            gemm_bf16<1, 0, 0, 1><<<dim3(SEQ / 128, 4224 / 128), 256, 0, stream>>>(
                u_b, DM, in_wT + (size_t)L * 4224 * DM, in_b + (size_t)L * 4096, nullptr, xr,
                xdbl, dlt_b, SEQ, 4224, DM);
        } else {
            gemm_f32<0><<<dim3(4096 / 64, SEQ / 64), dim3(16, 16), 0, stream>>>(
                u, DM, in_w + (size_t)L * DM * 4096, in_b + (size_t)L * 4096, nullptr, xr,
                SEQ, 4096, DM);
        }
        conv_silu_kernel<<<SEQ * DI / 256, 256, 0, stream>>>(
            xr, conv_w + (size_t)L * 4 * SEQ, conv_b + (size_t)L * SEQ, xc);
        if (mid) {
            gemm_bf16<1, 0, 1, 0><<<dim3(SEQ / 128, DI / 128), 256, 0, stream>>>(
                dlt_b, 64, dt_wT + (size_t)L * DI * 64, dt_b + (size_t)L * DI, nullptr, delta,
                nullptr, nullptr, SEQ, DI, 64);
        } else {
            xproj_kernel<<<SEQ / 4, 128, 0, stream>>>(u, x_proj_w + (size_t)L * DM * 96, xdbl);
            gemm_f32<1><<<dim3(DI / 64, SEQ / 64), dim3(16, 16), 0, stream>>>(
                xdbl, 128, dt_w + (size_t)L * DTR * DI, dt_b + (size_t)L * DI, nullptr, delta,
                SEQ, DI, DTR);
        }
        scan_p1<<<dim3(NC, DI / 256), 256, 0, stream>>>(
            xc, delta, xdbl, A_log + (size_t)L * DI * DST, Pbuf, Sbuf);
        scan_p2<<<DI * 16 / 256, 256, 0, stream>>>(Pbuf, Sbuf, Xbuf);
        scan_p3<<<dim3(NC, DI / 256), 256, 0, stream>>>(
            xc, delta, xdbl, A_log + (size_t)L * DI * DST, Dp + (size_t)L * DI, Xbuf, xr,
            y, y_b);
        if (mid) {
            gemm_bf16<1, 1, 0, 0><<<dim3(SEQ / 128, DM / 128), 256, 0, stream>>>(
                y_b, DI, out_wT + (size_t)L * DM * DI, out_b + (size_t)L * DM, h, h,
                nullptr, nullptr, SEQ, DM, DI);
        } else {
            ymul_silu<<<SEQ * DI / 256, 256, 0, stream>>>(y, xr);
            gemm_f32<0><<<dim3(DM / 64, SEQ / 64), dim3(16, 16), 0, stream>>>(
                y, DI, out_w + (size_t)L * DI * DM, out_b + (size_t)L * DM, h, h,
                SEQ, DM, DI);
        }
    }

    rmsnorm_kernel<<<SEQ, 256, 0, stream>>>(h, norm_f, hn, full ? hn_b : nullptr);
    if (full) {
        hipFuncSetAttribute((const void*)gemm_bf16_8ph,
                            hipFuncAttributeMaxDynamicSharedMemorySize, 131072);
        gemm_bf16_8ph<<<dim3(SEQ / 256, NVOCP / 256), 512, 131072, stream>>>(
            hn_b, lm_wT, out, SEQ, NVOC, DM);
    } else {
        gemm_f32<0><<<dim3(NVOC / 64, SEQ / 64), dim3(16, 16), 0, stream>>>(
            hn, DM, lm_w, nullptr, nullptr, out, SEQ, NVOC, DM);
    }
}